// Round 3
// baseline (387.943 us; speedup 1.0000x reference)
//
#include <hip/hip_runtime.h>

typedef __attribute__((ext_vector_type(8))) short short8;
typedef __attribute__((ext_vector_type(16))) float f32x16;

#define B_    8
#define CI    256
#define CO    256
#define Hh    160
#define Ww    160
#define HP    162
#define WP    162
#define HWp   (Hh * Ww)                 // 25600
#define XPAD_ELEMS (B_ * HP * WP * CI)  // 53,747,712 bf16
#define W3_ELEMS   (9 * CI * CO)        // 589,824 bf16 (fragment-ordered)
#define NT    36                        // K-tiles: 9 shifts x 4 ci-chunks, BK=64
#define BPX   128                       // pixels per block
#define NBLK  1600                      // 204800 / 128

__device__ __forceinline__ unsigned short f2bf(float f) {
  unsigned int u = __float_as_uint(f);
  u += 0x7FFFu + ((u >> 16) & 1u);   // RNE
  return (unsigned short)(u >> 16);
}

// weight [co][ci][3][3] f32 -> w3 in 32x32x16 A-fragment order:
// idx = ((((tt)*8 + mt)*4 + s)*64 + lane)*8 + e
//   tt = shift*4 + cic ; co = mt*32 + (lane&31) ; ci = cic*64 + s*16 + (lane>>5)*8 + e
__global__ void prep_w_kernel(const float* __restrict__ w, unsigned short* __restrict__ w3) {
  int i = blockIdx.x * 256 + threadIdx.x;
  if (i >= W3_ELEMS) return;
  int e = i & 7;
  int l = (i >> 3) & 63;
  int s = (i >> 9) & 3;
  int mt = (i >> 11) & 7;
  int tt = i >> 14;
  int shift = tt >> 2;
  int cic = tt & 3;
  int co = mt * 32 + (l & 31);
  int ci = cic * 64 + s * 16 + (l >> 5) * 8 + e;
  w3[i] = f2bf(w[(co * 256 + ci) * 9 + shift]);
}

// zero the padded border of xp (rows 0,161 and cols 0,161 per image)
__global__ void zero_border(unsigned short* __restrict__ xp) {
  int g = blockIdx.x * 256 + threadIdx.x;
  int pos = g >> 5;
  int c = (g & 31) << 3;
  int n = pos / 644;
  int p = pos - n * 644;
  int y, x;
  if (p < 324) { y = (p < 162) ? 0 : 161; x = (p < 162) ? p : p - 162; }
  else { int q = p - 324; y = 1 + (q >> 1); x = (q & 1) ? 161 : 0; }
  unsigned short* d = xp + (((size_t)(n * 162 + y)) * 162 + x) * 256 + c;
  *(uint4*)d = (uint4){0u, 0u, 0u, 0u};
}

// ori [n][ci][h][w] f32 * mask [n][1][h][w] -> xp [n][h+1][w+1][ci] bf16 (padded NHWC)
__global__ void prep_x_kernel(const float* __restrict__ ori, const int* __restrict__ mask,
                              unsigned short* __restrict__ xp) {
  int bid = blockIdx.x;                 // ((n*160+h)*4+cit)*3+wt
  int wt = bid % 3;
  int t1 = bid / 3;
  int cit = t1 & 3;
  int t2 = t1 >> 2;
  int h = t2 % Hh;
  int n = t2 / Hh;
  int t = threadIdx.x;

  __shared__ float tile[64][65];

  int wl = t & 63;
  int w = wt * 64 + wl;
  bool valid = (w < Ww);
  float m = 0.f;
  if (valid) m = (float)mask[(n * Hh + h) * Ww + w];
  const float* src = ori + (((size_t)(n * CI + cit * 64) * Hh + h) * Ww + w);
  int r0 = t >> 6;
#pragma unroll
  for (int k = 0; k < 16; ++k) {
    int ci_l = r0 * 16 + k;
    float v = 0.f;
    if (valid) v = src[(size_t)ci_l * HWp] * m;
    tile[ci_l][wl] = v;
  }
  __syncthreads();

  int wl2 = t >> 2;
  int wo = wt * 64 + wl2;
  if (wo < Ww) {
    int cseg = (t & 3) * 16;
    union { unsigned short u[8]; uint4 v; } p0, p1;
#pragma unroll
    for (int j = 0; j < 8; ++j) p0.u[j] = f2bf(tile[cseg + j][wl2]);
#pragma unroll
    for (int j = 0; j < 8; ++j) p1.u[j] = f2bf(tile[cseg + 8 + j][wl2]);
    unsigned short* dst = xp + ((size_t)((n * HP + h + 1) * WP) + (wo + 1)) * CI + cit * 64 + cseg;
    *(uint4*)dst = p0.v;
    *(uint4*)(dst + 8) = p1.v;
  }
}

__device__ __forceinline__ void gload16(const unsigned short* g, unsigned short* l) {
  __builtin_amdgcn_global_load_lds((const __attribute__((address_space(1))) void*)g,
                                   (__attribute__((address_space(3))) void*)l, 16, 0, 0);
}

// Implicit GEMM, 32x32x16 MFMA, A(weights) direct-to-reg, B(pixels) in LDS.
// Block: 256co x 128px, 256 threads = 4 waves (4-way m-split), per-wave 64co x 128px.
// acc[2][4] f32x16 (128 VGPR). LDS: B only, 2 x 16KB double buffer.
// B LDS swizzle: 16B-slot j of px-row r holds global slot j ^ (r&7).
__global__ void __launch_bounds__(256, 2) sconv_gemm(const unsigned short* __restrict__ xp,
                                                     const unsigned short* __restrict__ w3,
                                                     const float* __restrict__ bias,
                                                     float* __restrict__ out) {
  __shared__ unsigned short Bs[2][BPX * 64];   // 16KB per slot

  // XCD-chunked swizzle: XCD k gets blocks [200k, 200k+200) = image k
  int braw = blockIdx.x;
  int bid = (braw & 7) * (NBLK / 8) + (braw >> 3);
  const int p0 = bid * BPX;

  const int t = threadIdx.x;
  const int l = t & 63;
  const int wv = t >> 6;            // m-quarter: co base = wv*64

  // ---- B staging addresses (4 rounds of 8 px-rows per wave) ----
  // round rr: px_local = wv*32 + rr*8 + (l>>3); LDS dest linear (lane slot l&7);
  // global source pre-swizzled: slot (l&7)^(l>>3)
  unsigned boff[4];
#pragma unroll
  for (int rr = 0; rr < 4; ++rr) {
    int pxl = wv * 32 + rr * 8 + (l >> 3);
    int p = p0 + pxl;
    int n = p / HWp;
    int hw = p - n * HWp;
    int h = hw / Ww;
    int w = hw - h * Ww;
    boff[rr] = (unsigned)((n * HP + h) * WP + w) * CI + (((l & 7) ^ (l >> 3)) << 3);
  }

  // B fragment read: row = ni*32 + (l&31); slot = (2s + (l>>5)) ^ (l&7)
  const int brow = (l & 31) * 64;
  const int bx = l & 7;
  const int bhi = l >> 5;

  f32x16 acc[2][4];
#pragma unroll
  for (int mi = 0; mi < 2; ++mi)
#pragma unroll
    for (int ni = 0; ni < 4; ++ni)
      acc[mi][ni] = (f32x16)(0.f);

  auto STAGE = [&](int tt) {
    int shift = tt >> 2;
    int kh = shift / 3;
    int kw = shift - kh * 3;
    unsigned bd = (unsigned)(kh * WP + kw) * CI + ((tt & 3) << 6);
    unsigned short* sb = &Bs[tt & 1][(wv * 32) * 64];
#pragma unroll
    for (int rr = 0; rr < 4; ++rr)
      gload16(xp + boff[rr] + bd, sb + rr * 512);
  };

  STAGE(0);
  STAGE(1);
  asm volatile("s_waitcnt vmcnt(4)" ::: "memory");   // slot 0 landed; slot 1 in flight
  __builtin_amdgcn_s_barrier();

  for (int tt = 0; tt < NT; ++tt) {
    // A fragments for this tile: 8 coalesced 16B loads from L2-resident w3
    short8 a[2][4];
#pragma unroll
    for (int mi = 0; mi < 2; ++mi)
#pragma unroll
      for (int s = 0; s < 4; ++s)
        a[mi][s] = *(const short8*)(w3 + ((size_t)(((tt * 8 + (wv * 2 + mi)) * 4 + s) * 64 + l) << 3));

    const unsigned short* Bb = Bs[tt & 1];
#pragma unroll
    for (int s = 0; s < 4; ++s) {
      short8 bf[4];
#pragma unroll
      for (int ni = 0; ni < 4; ++ni)
        bf[ni] = *(const short8*)(Bb + ni * 2048 + brow + ((((s << 1) + bhi) ^ bx) << 3));
      __builtin_amdgcn_s_setprio(1);
#pragma unroll
      for (int mi = 0; mi < 2; ++mi)
#pragma unroll
        for (int ni = 0; ni < 4; ++ni)
          acc[mi][ni] = __builtin_amdgcn_mfma_f32_32x32x16_bf16(a[mi][s], bf[ni], acc[mi][ni], 0, 0, 0);
      __builtin_amdgcn_s_setprio(0);
    }

    __syncthreads();                  // drains STAGE(tt+1) (in flight one full phase)
    if (tt + 2 < NT) STAGE(tt + 2);
  }

  // ---- epilogue: C/D 32x32 layout: col(px)=l&31, row(co)=(q&3)+8*(q>>2)+4*(l>>5) ----
  float4 bv[2][4];
#pragma unroll
  for (int mi = 0; mi < 2; ++mi)
#pragma unroll
    for (int g = 0; g < 4; ++g)
      bv[mi][g] = *(const float4*)(bias + wv * 64 + mi * 32 + g * 8 + 4 * bhi);

#pragma unroll
  for (int ni = 0; ni < 4; ++ni) {
    int p = p0 + ni * 32 + (l & 31);
    int n = p / HWp;
    int hw = p - n * HWp;
    float* op = out + (size_t)n * (CO * HWp) + hw;
#pragma unroll
    for (int mi = 0; mi < 2; ++mi) {
      int cob = wv * 64 + mi * 32 + 4 * bhi;
#pragma unroll
      for (int g = 0; g < 4; ++g) {
#pragma unroll
        for (int r = 0; r < 4; ++r) {
          int q = g * 4 + r;
          int co = cob + r + 8 * g;
          op[(size_t)co * HWp] = acc[mi][ni][q] + ((const float*)&bv[mi][g])[r];
        }
      }
    }
  }
}

extern "C" void kernel_launch(void* const* d_in, const int* in_sizes, int n_in,
                              void* d_out, int out_size, void* d_ws, size_t ws_size,
                              hipStream_t stream) {
  const int* mask = (const int*)d_in[0];
  const float* ori = (const float*)d_in[1];
  const float* weight = (const float*)d_in[2];
  const float* bias = (const float*)d_in[3];
  float* out = (float*)d_out;

  unsigned short* xp = (unsigned short*)d_ws;          // padded NHWC bf16, 107.5 MB
  unsigned short* w3 = xp + XPAD_ELEMS;                // 1.2 MB fragment-ordered weights

  zero_border<<<644, 256, 0, stream>>>(xp);
  prep_w_kernel<<<(W3_ELEMS + 255) / 256, 256, 0, stream>>>(weight, w3);
  prep_x_kernel<<<B_ * Hh * 4 * 3, 256, 0, stream>>>(ori, mask, xp);
  sconv_gemm<<<NBLK, 256, 0, stream>>>(xp, w3, bias, out);
}